// Round 17
// baseline (157.376 us; speedup 1.0000x reference)
//
#include <hip/hip_runtime.h>
#include <hip/hip_fp16.h>

// LatticeMultiHeadAttention — B=2, L=2048, D=1024, H=16, DK=64.
//
// Phase/bias computation skipped (exact): per-head constant bias cancels in
// softmax; masked scores (-10000) underflow to 0 regardless of bias.
//
// Round 17: flash SPLIT-K attention — grid 512->1024 blocks (each does half
// the keys), filling the 3-blocks/CU the r14 LDS swizzle enabled (12 waves/CU
// vs 8; attn was issue-bound at 18.6% occupancy). Halves write normalized
// O_half + per-q (m,l); a merge kernel combines. qkv/out_proj = r15 verbatim
// (5 structural variants all ~77us => shape ceiling of this structure).

#define B_ 2
#define L_ 2048
#define D_ 1024
#define H_ 16
#define DK_ 64

// 0.125 * log2(e): QK^T scale folded into Q projection, softmax in exp2 domain.
#define QSCALE 0.1803368801111244f
#define MASKOFF -14427.0f

typedef _Float16 f16;
typedef _Float16 f16x2 __attribute__((ext_vector_type(2)));
typedef _Float16 f16x4 __attribute__((ext_vector_type(4)));
typedef _Float16 f16x8 __attribute__((ext_vector_type(8)));
typedef __fp16 hf16x2 __attribute__((ext_vector_type(2)));
typedef float f32x4 __attribute__((ext_vector_type(4)));

// raw 2^x: valid here since x <= 0 (flush-to-zero is wanted)
static __device__ __forceinline__ float fast_exp2(float x) {
    float r;
    asm("v_exp_f32 %0, %1" : "=v"(r) : "v"(x));
    return r;
}

static __device__ __forceinline__ f16x4 pack4(float a, float b, float c, float d) {
    hf16x2 lo = __builtin_amdgcn_cvt_pkrtz(a, b);
    hf16x2 hi = __builtin_amdgcn_cvt_pkrtz(c, d);
    f16x2 l2 = __builtin_bit_cast(f16x2, lo);
    f16x2 h2 = __builtin_bit_cast(f16x2, hi);
    f16x4 o; o[0] = l2[0]; o[1] = l2[1]; o[2] = h2[0]; o[3] = h2[1];
    return o;
}

// ---------------------------------------------------------------------------
// QKV projection GEMM (f32 in, f16 out). BM=128, BK=64 as two BK=32
// sub-tiles (r15). Q,K -> [b,h,l,k]; V -> transposed [b,h,k,l].
// ---------------------------------------------------------------------------
__global__ __launch_bounds__(256) void qkv_proj_kernel(
    const float* __restrict__ query, const float* __restrict__ keyx,
    const float* __restrict__ value,
    const float* __restrict__ Wq, const float* __restrict__ Wk,
    const float* __restrict__ Wv,
    f16* __restrict__ Qh, f16* __restrict__ Kh, f16* __restrict__ VhT)
{
    const int z = blockIdx.z;
    const float* X = (z == 0) ? query : (z == 1) ? keyx : value;
    const float* W = (z == 0) ? Wq : (z == 1) ? Wk : Wv;
    f16* out = (z == 0) ? Qh : (z == 1) ? Kh : VhT;
    const float qs = (z == 0) ? QSCALE : 1.0f;

    const int m0 = blockIdx.x * 128;
    const int n0 = blockIdx.y * 128;
    const int tid = threadIdx.x;
    const int lane = tid & 63;
    const int w = tid >> 6;
    const int wr = (w >> 1) * 64, wc = (w & 1) * 64;

    __shared__ f16 As[2][128 * 40];
    __shared__ f16 Ws[2][128 * 40];

    f32x4 acc[4][4] = {};

    const int r = tid >> 3, c = (tid & 7) * 4;
    float4 ra[2][4], rb[2][4];

    auto issueK = [&](int kk) {
        #pragma unroll
        for (int s = 0; s < 2; ++s)
            #pragma unroll
            for (int p = 0; p < 4; ++p) {
                ra[s][p] = *(const float4*)&X[(size_t)(m0 + p * 32 + r) * D_ + kk + s * 32 + c];
                rb[s][p] = *(const float4*)&W[(size_t)(n0 + p * 32 + r) * D_ + kk + s * 32 + c];
            }
    };
    auto storeK = [&]() {
        #pragma unroll
        for (int s = 0; s < 2; ++s)
            #pragma unroll
            for (int p = 0; p < 4; ++p) {
                int row = p * 32 + r;
                f16x4 ha = { (f16)(ra[s][p].x * qs), (f16)(ra[s][p].y * qs),
                             (f16)(ra[s][p].z * qs), (f16)(ra[s][p].w * qs) };
                *(f16x4*)&As[s][row * 40 + c] = ha;
                f16x4 hb = { (f16)rb[s][p].x, (f16)rb[s][p].y,
                             (f16)rb[s][p].z, (f16)rb[s][p].w };
                *(f16x4*)&Ws[s][row * 40 + c] = hb;
            }
    };

    issueK(0);
    for (int t = 0; t < 16; ++t) {
        __syncthreads();
        storeK();
        if (t + 1 < 16) issueK((t + 1) * 64);
        __syncthreads();

        const int lg = (lane >> 4) * 8;
        #pragma unroll
        for (int s = 0; s < 2; ++s) {
            f16x8 af[4], bf[4];
            #pragma unroll
            for (int i = 0; i < 4; ++i) {
                af[i] = *(const f16x8*)&As[s][(wr + i * 16 + (lane & 15)) * 40 + lg];
                bf[i] = *(const f16x8*)&Ws[s][(wc + i * 16 + (lane & 15)) * 40 + lg];
            }
            #pragma unroll
            for (int i = 0; i < 4; ++i)
                #pragma unroll
                for (int j = 0; j < 4; ++j)
                    acc[i][j] = __builtin_amdgcn_mfma_f32_16x16x32_f16(af[i], bf[j], acc[i][j], 0, 0, 0);
        }
    }

    if (z == 2) {
        #pragma unroll
        for (int i = 0; i < 4; ++i) {
            int grow = m0 + wr + i * 16 + (lane >> 4) * 4;
            int b = grow >> 11, l = grow & (L_ - 1);
            #pragma unroll
            for (int j = 0; j < 4; ++j) {
                int gcol = n0 + wc + j * 16 + (lane & 15);
                int hh = gcol >> 6, k = gcol & 63;
                f16x4 o = { (f16)acc[i][j][0], (f16)acc[i][j][1],
                            (f16)acc[i][j][2], (f16)acc[i][j][3] };
                *(f16x4*)&out[((size_t)((b * H_ + hh) * DK_ + k)) * L_ + l] = o;
            }
        }
    } else {
        #pragma unroll
        for (int i = 0; i < 4; ++i) {
            int grow = m0 + wr + i * 16 + (lane >> 4) * 4;
            #pragma unroll
            for (int j = 0; j < 4; ++j) {
                int gcol = n0 + wc + j * 16 + (lane & 15);
                int hh = gcol >> 6, k = gcol & 63;
                #pragma unroll
                for (int rr = 0; rr < 4; ++rr) {
                    int row = grow + rr;
                    int b = row >> 11, l = row & (L_ - 1);
                    out[(((size_t)(b * H_ + hh)) * L_ + l) * DK_ + k] = (f16)acc[i][j][rr];
                }
            }
        }
    }
}

// ---------------------------------------------------------------------------
// Flash attention, SPLIT-K over keys. 1024 blocks: half = n>>9 processes
// keys [half*1024, half*1024+1024). Per block: 4 waves x 32 q rows, 64-key
// tiles, double-buffered swizzled K/V LDS, 1 barrier/tile, fast_exp2.
// Writes normalized O_half + per-q (m, l) for the merge pass.
// ---------------------------------------------------------------------------
__global__ __launch_bounds__(256) void attn_kernel(
    const f16* __restrict__ Qh, const f16* __restrict__ Kh,
    const f16* __restrict__ VhT, const int* __restrict__ mask,
    f16* __restrict__ Ohalf, float* __restrict__ Mh, float* __restrict__ Lh)
{
    const int n = blockIdx.x;                    // 1024 blocks
    const int half = n >> 9;
    const int n2 = n & 511;
    const int bh = ((n2 >> 7) << 3) + (n2 & 7);  // b*H + h (XCD swizzle)
    const int qb = (n2 >> 3) & 15;
    const int b = bh >> 4, h = bh & 15;
    const int q0 = qb * 128;
    const int kbase = half * 1024;
    const int tid = threadIdx.x;
    const int lane = tid & 63;
    const int w = tid >> 6;
    const int lq = lane & 15, g = lane >> 4;

    __shared__ f16 Ks[2][64 * 64];
    __shared__ f16 Vt[2][64 * 64];
    __shared__ f16 Plds[4][32 * 72];
    __shared__ float mofft[2][64];

    const size_t base = (size_t)bh * L_ * DK_;
    const int* maskp = mask + b * L_;

    f16x8 qf0[2], qf1[2];
    {
        const f16* qptr = Qh + base + (size_t)(q0 + w * 32 + lq) * DK_ + g * 8;
        qf0[0] = *(const f16x8*)(qptr);
        qf0[1] = *(const f16x8*)(qptr + 32);
        qptr += 16 * DK_;
        qf1[0] = *(const f16x8*)(qptr);
        qf1[1] = *(const f16x8*)(qptr + 32);
    }

    const int srow = tid >> 2;              // staging row 0..63
    const int sslot = (tid & 3) * 2;        // logical 16B slot (even)
    const int ps0 = sslot ^ (srow & 7);
    const int ps1 = (sslot + 1) ^ (srow & 7);

    f32x4 acc0[4] = {}, acc1[4] = {};
    float mrun0 = -1e30f, lrun0 = 0.f;
    float mrun1 = -1e30f, lrun1 = 0.f;

    f16x8 kr0, kr1, vr0, vr1;

    auto issue = [&](int k0) {
        const f16* kp = Kh + base + (size_t)(k0 + srow) * DK_ + sslot * 8;
        kr0 = *(const f16x8*)kp;
        kr1 = *(const f16x8*)(kp + 8);
        const f16* vp = VhT + (size_t)(bh * DK_ + srow) * L_ + k0 + sslot * 8;
        vr0 = *(const f16x8*)vp;
        vr1 = *(const f16x8*)(vp + 8);
    };

    auto store_tile = [&](int buf, int k0) {
        *(f16x8*)&Ks[buf][srow * 64 + ps0 * 8] = kr0;
        *(f16x8*)&Ks[buf][srow * 64 + ps1 * 8] = kr1;
        *(f16x8*)&Vt[buf][srow * 64 + ps0 * 8] = vr0;
        *(f16x8*)&Vt[buf][srow * 64 + ps1 * 8] = vr1;
        if (tid < 16) {
            int4 mv = *(const int4*)&maskp[k0 + tid * 4];
            float4 f = { mv.x ? 0.f : MASKOFF, mv.y ? 0.f : MASKOFF,
                         mv.z ? 0.f : MASKOFF, mv.w ? 0.f : MASKOFF };
            *(float4*)&mofft[buf][tid * 4] = f;
        }
    };

    auto softmax_store = [&](float* sv, float& mrun, float& lrun,
                             f32x4* acc, int rowoff) {
        float a0 = fmaxf(sv[0], sv[1]),  a1 = fmaxf(sv[2], sv[3]);
        float a2 = fmaxf(sv[4], sv[5]),  a3 = fmaxf(sv[6], sv[7]);
        float a4 = fmaxf(sv[8], sv[9]),  a5 = fmaxf(sv[10], sv[11]);
        float a6 = fmaxf(sv[12], sv[13]), a7 = fmaxf(sv[14], sv[15]);
        float m = fmaxf(fmaxf(fmaxf(a0, a1), fmaxf(a2, a3)),
                        fmaxf(fmaxf(a4, a5), fmaxf(a6, a7)));
        m = fmaxf(m, __shfl_xor(m, 16, 64));
        m = fmaxf(m, __shfl_xor(m, 32, 64));
        if (__any(m > mrun)) {
            float mn = fmaxf(mrun, m);
            float scl = fast_exp2(mrun - mn);
            mrun = mn;
            lrun *= scl;
            #pragma unroll
            for (int f = 0; f < 4; ++f) acc[f] *= scl;
        }
        f16* pl = (f16*)Plds[w];
        float ls0 = 0.f, ls1 = 0.f;
        #pragma unroll
        for (int kt = 0; kt < 4; ++kt) {
            float p0 = fast_exp2(sv[kt * 4 + 0] - mrun);
            float p1 = fast_exp2(sv[kt * 4 + 1] - mrun);
            float p2 = fast_exp2(sv[kt * 4 + 2] - mrun);
            float p3 = fast_exp2(sv[kt * 4 + 3] - mrun);
            ls0 += p0 + p1;
            ls1 += p2 + p3;
            f16x4 pk = pack4(p0, p1, p2, p3);
            *(f16x4*)&pl[(rowoff + lq) * 72 + kt * 16 + g * 4] = pk;
        }
        lrun += ls0 + ls1;
    };

    auto compute = [&](int buf) {
        float sv0[16], sv1[16];
        __builtin_amdgcn_s_setprio(1);
        #pragma unroll
        for (int kt = 0; kt < 4; ++kt) {
            f32x4 cin = *(const f32x4*)&mofft[buf][kt * 16 + g * 4];
            int row = kt * 16 + lq;
            const f16* kb = &Ks[buf][row * 64];
            f16x8 a0 = *(const f16x8*)&kb[(g ^ (row & 7)) * 8];
            f16x8 a1 = *(const f16x8*)&kb[((g + 4) ^ (row & 7)) * 8];
            f32x4 s0 = __builtin_amdgcn_mfma_f32_16x16x32_f16(a0, qf0[0], cin, 0, 0, 0);
            s0 = __builtin_amdgcn_mfma_f32_16x16x32_f16(a1, qf0[1], s0, 0, 0, 0);
            f32x4 s1 = __builtin_amdgcn_mfma_f32_16x16x32_f16(a0, qf1[0], cin, 0, 0, 0);
            s1 = __builtin_amdgcn_mfma_f32_16x16x32_f16(a1, qf1[1], s1, 0, 0, 0);
            *(f32x4*)&sv0[kt * 4] = s0;
            *(f32x4*)&sv1[kt * 4] = s1;
        }
        __builtin_amdgcn_s_setprio(0);

        softmax_store(sv0, mrun0, lrun0, acc0, 0);
        softmax_store(sv1, mrun1, lrun1, acc1, 16);
        asm volatile("s_waitcnt lgkmcnt(0)" ::: "memory");
        __builtin_amdgcn_sched_barrier(0);

        f16* pl = (f16*)Plds[w];
        __builtin_amdgcn_s_setprio(1);
        #pragma unroll
        for (int kc = 0; kc < 2; ++kc) {
            f16x8 pb0 = *(const f16x8*)&pl[lq * 72 + kc * 32 + g * 8];
            f16x8 pb1 = *(const f16x8*)&pl[(16 + lq) * 72 + kc * 32 + g * 8];
            #pragma unroll
            for (int f = 0; f < 4; ++f) {
                int row = f * 16 + lq;
                f16x8 va = *(const f16x8*)&Vt[buf][row * 64 + ((kc * 4 + g) ^ (row & 7)) * 8];
                acc0[f] = __builtin_amdgcn_mfma_f32_16x16x32_f16(va, pb0, acc0[f], 0, 0, 0);
                acc1[f] = __builtin_amdgcn_mfma_f32_16x16x32_f16(va, pb1, acc1[f], 0, 0, 0);
            }
        }
        __builtin_amdgcn_s_setprio(0);
    };

    issue(kbase);
    store_tile(0, kbase);
    issue(kbase + 64);
    __syncthreads();

    #pragma unroll 2
    for (int t = 0; t < 16; ++t) {
        int buf = t & 1;
        if (t + 1 < 16) store_tile(buf ^ 1, kbase + (t + 1) * 64);
        if (t + 2 < 16) issue(kbase + (t + 2) * 64);
        compute(buf);
        __syncthreads();
    }

    // epilogue: reduce partial lrun, store normalized O_half + (m,l)
    lrun0 += __shfl_xor(lrun0, 16, 64);
    lrun0 += __shfl_xor(lrun0, 32, 64);
    lrun1 += __shfl_xor(lrun1, 16, 64);
    lrun1 += __shfl_xor(lrun1, 32, 64);

    f16* Ohp = Ohalf + (size_t)half * (B_ * L_ * D_);
    {
        float inv = 1.f / lrun0;
        int q = q0 + w * 32 + lq;
        #pragma unroll
        for (int f = 0; f < 4; ++f) {
            f16x4 o = { (f16)(acc0[f][0] * inv), (f16)(acc0[f][1] * inv),
                        (f16)(acc0[f][2] * inv), (f16)(acc0[f][3] * inv) };
            *(f16x4*)&Ohp[((size_t)(b * L_ + q)) * D_ + h * 64 + f * 16 + g * 4] = o;
        }
    }
    {
        float inv = 1.f / lrun1;
        int q = q0 + w * 32 + 16 + lq;
        #pragma unroll
        for (int f = 0; f < 4; ++f) {
            f16x4 o = { (f16)(acc1[f][0] * inv), (f16)(acc1[f][1] * inv),
                        (f16)(acc1[f][2] * inv), (f16)(acc1[f][3] * inv) };
            *(f16x4*)&Ohp[((size_t)(b * L_ + q)) * D_ + h * 64 + f * 16 + g * 4] = o;
        }
    }
    if (g == 0) {
        int q = q0 + w * 32 + lq;
        int mlbase = half * (32 * L_) + bh * L_;
        Mh[mlbase + q] = mrun0;
        Lh[mlbase + q] = lrun0;
        Mh[mlbase + q + 16] = mrun1;
        Lh[mlbase + q + 16] = lrun1;
    }
}

// ---------------------------------------------------------------------------
// Split-K merge: O = (w1*O1 + w2*O2)/(w1+w2), wi = li * 2^(mi - mmax).
// One block per (b,l) row; thread -> 4 f16.
// ---------------------------------------------------------------------------
__global__ __launch_bounds__(256) void merge_kernel(
    const f16* __restrict__ Ohalf, const float* __restrict__ Mh,
    const float* __restrict__ Lh, f16* __restrict__ Oh)
{
    const int row = blockIdx.x;          // b*L + l
    const int b = row >> 11, l = row & (L_ - 1);
    const int i = threadIdx.x * 4;
    const int h = i >> 6;
    const int idx = (b * H_ + h) * L_ + l;

    float m1 = Mh[idx],             l1 = Lh[idx];
    float m2 = Mh[32 * L_ + idx],   l2 = Lh[32 * L_ + idx];
    float mx = fmaxf(m1, m2);
    float w1 = l1 * fast_exp2(m1 - mx);
    float w2 = l2 * fast_exp2(m2 - mx);
    float inv = 1.f / (w1 + w2);
    w1 *= inv; w2 *= inv;

    f16x4 a = *(const f16x4*)&Ohalf[(size_t)row * D_ + i];
    f16x4 c = *(const f16x4*)&Ohalf[(size_t)(B_ * L_) * D_ + (size_t)row * D_ + i];
    f16x4 o;
    #pragma unroll
    for (int j = 0; j < 4; ++j)
        o[j] = (f16)(w1 * (float)a[j] + w2 * (float)c[j]);
    *(f16x4*)&Oh[(size_t)row * D_ + i] = o;
}

// ---------------------------------------------------------------------------
// Output projection GEMM (+bias), f32 out. BK=64 as two BK=32 sub-tiles (r15).
// ---------------------------------------------------------------------------
__global__ __launch_bounds__(256) void out_proj_kernel(
    const f16* __restrict__ Oh, const float* __restrict__ outw,
    const float* __restrict__ outb, float* __restrict__ Y)
{
    const int m0 = blockIdx.x * 128;
    const int n0 = blockIdx.y * 128;
    const int tid = threadIdx.x;
    const int lane = tid & 63;
    const int w = tid >> 6;
    const int wr = (w >> 1) * 64, wc = (w & 1) * 64;

    __shared__ f16 As[2][128 * 40];
    __shared__ f16 Ws[2][128 * 40];

    f32x4 acc[4][4] = {};

    const int r = tid >> 3, c = (tid & 7) * 4;
    f16x4 ra[2][4];
    float4 rb[2][4];

    auto issueK = [&](int kk) {
        #pragma unroll
        for (int s = 0; s < 2; ++s)
            #pragma unroll
            for (int p = 0; p < 4; ++p) {
                ra[s][p] = *(const f16x4*)&Oh[(size_t)(m0 + p * 32 + r) * D_ + kk + s * 32 + c];
                rb[s][p] = *(const float4*)&outw[(size_t)(n0 + p * 32 + r) * D_ + kk + s * 32 + c];
            }
    };
    auto storeK = [&]() {
        #pragma unroll
        for (int s = 0; s < 2; ++s)
            #pragma unroll
            for (int p = 0; p < 4; ++p) {
                int row = p * 32 + r;
                *(f16x4*)&As[s][row * 40 + c] = ra[s][p];
                f16x4 hb = { (f16)rb[s][p].x, (f16)rb[s][p].y,
                             (f16)rb[s][p].z, (f16)rb[s][p].w };
                *(f16x4*)&Ws[s][row * 40 + c] = hb;
            }
    };

    issueK(0);
    for (int t = 0; t < 16; ++t) {
        __syncthreads();
        storeK();
        if (t + 1 < 16) issueK((t + 1) * 64);
        __syncthreads();

        const int lg = (lane >> 4) * 8;
        #pragma unroll
        for (int s = 0; s < 2; ++s) {
            f16x8 af[4], bf[4];
            #pragma unroll
            for (int i = 0; i < 4; ++i) {
                af[i] = *(const f16x8*)&As[s][(wr + i * 16 + (lane & 15)) * 40 + lg];
                bf[i] = *(const f16x8*)&Ws[s][(wc + i * 16 + (lane & 15)) * 40 + lg];
            }
            #pragma unroll
            for (int i = 0; i < 4; ++i)
                #pragma unroll
                for (int j = 0; j < 4; ++j)
                    acc[i][j] = __builtin_amdgcn_mfma_f32_16x16x32_f16(af[i], bf[j], acc[i][j], 0, 0, 0);
        }
    }

    #pragma unroll
    for (int i = 0; i < 4; ++i) {
        int grow = m0 + wr + i * 16 + (lane >> 4) * 4;
        #pragma unroll
        for (int j = 0; j < 4; ++j) {
            int gcol = n0 + wc + j * 16 + (lane & 15);
            float bias = outb[gcol];
            #pragma unroll
            for (int rr = 0; rr < 4; ++rr)
                Y[(size_t)(grow + rr) * D_ + gcol] = acc[i][j][rr] + bias;
        }
    }
}

extern "C" void kernel_launch(void* const* d_in, const int* in_sizes, int n_in,
                              void* d_out, int out_size, void* d_ws, size_t ws_size,
                              hipStream_t stream) {
    const float* query = (const float*)d_in[0];
    const float* key   = (const float*)d_in[1];
    const float* value = (const float*)d_in[2];
    const float* Wq    = (const float*)d_in[3];
    const float* Wk    = (const float*)d_in[4];
    const float* Wv    = (const float*)d_in[5];
    const float* outw  = (const float*)d_in[7];
    const float* outb  = (const float*)d_in[8];
    const int*   mask  = (const int*)d_in[10];
    float* Y = (float*)d_out;

    char* ws = (char*)d_ws;
    f16* Qh    = (f16*)(ws);                //  [0,8M): [b,h,l,k] f16 (pre-scaled)
    f16* Kh    = (f16*)(ws + 8388608);      //  [8,16M): [b,h,l,k]
    f16* VhT   = (f16*)(ws + 16777216);     //  [16,24M): [b,h,k,l]
    f16* Oh    = (f16*)(ws + 25165824);     //  [24,32M): merged [b,l,h*64+k]
    f16* Ohalf = (f16*)(ws + 33554432);     //  [32,48M): two half outputs
    float* Mh  = (float*)(ws + 50331648);   //  [48M+):   [2][32][L] running max
    float* Lh  = (float*)(ws + 50855936);   //            [2][32][L] running sum

    qkv_proj_kernel<<<dim3(32, 8, 3), 256, 0, stream>>>(query, key, value,
                                                        Wq, Wk, Wv, Qh, Kh, VhT);
    attn_kernel<<<dim3(1024), 256, 0, stream>>>(Qh, Kh, VhT, mask, Ohalf, Mh, Lh);
    merge_kernel<<<dim3(4096), 256, 0, stream>>>(Ohalf, Mh, Lh, Oh);
    out_proj_kernel<<<dim3(32, 8), 256, 0, stream>>>(Oh, outw, outb, Y);
}

// Round 18
// 147.645 us; speedup vs baseline: 1.0659x; 1.0659x over previous
//
#include <hip/hip_runtime.h>
#include <hip/hip_fp16.h>

// LatticeMultiHeadAttention — B=2, L=2048, D=1024, H=16, DK=64.
//
// Phase/bias computation skipped (exact): per-head constant bias cancels in
// softmax; masked scores (-10000) underflow to 0 regardless of bias.
//
// Round 18 = round 15 verbatim (measured best: 148.0us). Split-K (r17),
// BM=64 (r16), f16-DMA (r13) all regressed or were null — this closes the
// session at the best-known configuration:
//   qkv: BM=128 BK=64 (two BK=32 sub-tiles), reg-prefetch, V^T epilogue
//   attn: 4 waves x 32q, swizzled K/V LDS dbuf, 1 barrier/tile, fast_exp2
//   out: BK=64, reg-prefetch

#define B_ 2
#define L_ 2048
#define D_ 1024
#define H_ 16
#define DK_ 64

// 0.125 * log2(e): QK^T scale folded into Q projection, softmax in exp2 domain.
#define QSCALE 0.1803368801111244f
#define MASKOFF -14427.0f

typedef _Float16 f16;
typedef _Float16 f16x2 __attribute__((ext_vector_type(2)));
typedef _Float16 f16x4 __attribute__((ext_vector_type(4)));
typedef _Float16 f16x8 __attribute__((ext_vector_type(8)));
typedef __fp16 hf16x2 __attribute__((ext_vector_type(2)));
typedef float f32x4 __attribute__((ext_vector_type(4)));

// raw 2^x: valid here since x <= 0 and x >= -14500 (flush-to-zero is wanted)
static __device__ __forceinline__ float fast_exp2(float x) {
    float r;
    asm("v_exp_f32 %0, %1" : "=v"(r) : "v"(x));
    return r;
}

static __device__ __forceinline__ f16x4 pack4(float a, float b, float c, float d) {
    hf16x2 lo = __builtin_amdgcn_cvt_pkrtz(a, b);
    hf16x2 hi = __builtin_amdgcn_cvt_pkrtz(c, d);
    f16x2 l2 = __builtin_bit_cast(f16x2, lo);
    f16x2 h2 = __builtin_bit_cast(f16x2, hi);
    f16x4 o; o[0] = l2[0]; o[1] = l2[1]; o[2] = h2[0]; o[3] = h2[1];
    return o;
}

// ---------------------------------------------------------------------------
// QKV projection GEMM (f32 in, f16 out). BK=64 as two BK=32 sub-tiles;
// 2 barriers per 64-K step (16 steps), depth-1 reg prefetch across the
// 32-MFMA compute phase. Q,K -> [b,h,l,k]; V -> transposed [b,h,k,l].
// ---------------------------------------------------------------------------
__global__ __launch_bounds__(256) void qkv_proj_kernel(
    const float* __restrict__ query, const float* __restrict__ keyx,
    const float* __restrict__ value,
    const float* __restrict__ Wq, const float* __restrict__ Wk,
    const float* __restrict__ Wv,
    f16* __restrict__ Qh, f16* __restrict__ Kh, f16* __restrict__ VhT)
{
    const int z = blockIdx.z;
    const float* X = (z == 0) ? query : (z == 1) ? keyx : value;
    const float* W = (z == 0) ? Wq : (z == 1) ? Wk : Wv;
    f16* out = (z == 0) ? Qh : (z == 1) ? Kh : VhT;
    const float qs = (z == 0) ? QSCALE : 1.0f;

    const int m0 = blockIdx.x * 128;
    const int n0 = blockIdx.y * 128;
    const int tid = threadIdx.x;
    const int lane = tid & 63;
    const int w = tid >> 6;
    const int wr = (w >> 1) * 64, wc = (w & 1) * 64;

    __shared__ f16 As[2][128 * 40];
    __shared__ f16 Ws[2][128 * 40];

    f32x4 acc[4][4] = {};

    const int r = tid >> 3, c = (tid & 7) * 4;
    float4 ra[2][4], rb[2][4];

    auto issueK = [&](int kk) {
        #pragma unroll
        for (int s = 0; s < 2; ++s)
            #pragma unroll
            for (int p = 0; p < 4; ++p) {
                ra[s][p] = *(const float4*)&X[(size_t)(m0 + p * 32 + r) * D_ + kk + s * 32 + c];
                rb[s][p] = *(const float4*)&W[(size_t)(n0 + p * 32 + r) * D_ + kk + s * 32 + c];
            }
    };
    auto storeK = [&]() {
        #pragma unroll
        for (int s = 0; s < 2; ++s)
            #pragma unroll
            for (int p = 0; p < 4; ++p) {
                int row = p * 32 + r;
                f16x4 ha = { (f16)(ra[s][p].x * qs), (f16)(ra[s][p].y * qs),
                             (f16)(ra[s][p].z * qs), (f16)(ra[s][p].w * qs) };
                *(f16x4*)&As[s][row * 40 + c] = ha;
                f16x4 hb = { (f16)rb[s][p].x, (f16)rb[s][p].y,
                             (f16)rb[s][p].z, (f16)rb[s][p].w };
                *(f16x4*)&Ws[s][row * 40 + c] = hb;
            }
    };

    issueK(0);
    for (int t = 0; t < 16; ++t) {
        __syncthreads();
        storeK();
        if (t + 1 < 16) issueK((t + 1) * 64);   // in flight across 32 MFMA
        __syncthreads();

        const int lg = (lane >> 4) * 8;
        #pragma unroll
        for (int s = 0; s < 2; ++s) {
            f16x8 af[4], bf[4];
            #pragma unroll
            for (int i = 0; i < 4; ++i) {
                af[i] = *(const f16x8*)&As[s][(wr + i * 16 + (lane & 15)) * 40 + lg];
                bf[i] = *(const f16x8*)&Ws[s][(wc + i * 16 + (lane & 15)) * 40 + lg];
            }
            #pragma unroll
            for (int i = 0; i < 4; ++i)
                #pragma unroll
                for (int j = 0; j < 4; ++j)
                    acc[i][j] = __builtin_amdgcn_mfma_f32_16x16x32_f16(af[i], bf[j], acc[i][j], 0, 0, 0);
        }
    }

    if (z == 2) {
        #pragma unroll
        for (int i = 0; i < 4; ++i) {
            int grow = m0 + wr + i * 16 + (lane >> 4) * 4;
            int b = grow >> 11, l = grow & (L_ - 1);
            #pragma unroll
            for (int j = 0; j < 4; ++j) {
                int gcol = n0 + wc + j * 16 + (lane & 15);
                int hh = gcol >> 6, k = gcol & 63;
                f16x4 o = { (f16)acc[i][j][0], (f16)acc[i][j][1],
                            (f16)acc[i][j][2], (f16)acc[i][j][3] };
                *(f16x4*)&out[((size_t)((b * H_ + hh) * DK_ + k)) * L_ + l] = o;
            }
        }
    } else {
        #pragma unroll
        for (int i = 0; i < 4; ++i) {
            int grow = m0 + wr + i * 16 + (lane >> 4) * 4;
            #pragma unroll
            for (int j = 0; j < 4; ++j) {
                int gcol = n0 + wc + j * 16 + (lane & 15);
                int hh = gcol >> 6, k = gcol & 63;
                #pragma unroll
                for (int rr = 0; rr < 4; ++rr) {
                    int row = grow + rr;
                    int b = row >> 11, l = row & (L_ - 1);
                    out[(((size_t)(b * H_ + hh)) * L_ + l) * DK_ + k] = (f16)acc[i][j][rr];
                }
            }
        }
    }
}

// ---------------------------------------------------------------------------
// Flash attention (r14). 4 waves x 32 q rows, 64-key tiles, double-buffered
// K/V LDS with stride-64 XOR slot-swizzle, 1 barrier/tile, per-lane partial
// lrun, fast_exp2 softmax.
// ---------------------------------------------------------------------------
__global__ __launch_bounds__(256) void attn_kernel(
    const f16* __restrict__ Qh, const f16* __restrict__ Kh,
    const f16* __restrict__ VhT, const int* __restrict__ mask,
    f16* __restrict__ Oh)
{
    const int n = blockIdx.x;                    // 512 blocks
    const int bh = ((n >> 7) << 3) + (n & 7);    // b*H + h
    const int qb = (n >> 3) & 15;
    const int b = bh >> 4, h = bh & 15;
    const int q0 = qb * 128;
    const int tid = threadIdx.x;
    const int lane = tid & 63;
    const int w = tid >> 6;
    const int lq = lane & 15, g = lane >> 4;

    __shared__ f16 Ks[2][64 * 64];
    __shared__ f16 Vt[2][64 * 64];
    __shared__ f16 Plds[4][32 * 72];
    __shared__ float mofft[2][64];

    const size_t base = (size_t)bh * L_ * DK_;
    const int* maskp = mask + b * L_;

    f16x8 qf0[2], qf1[2];
    {
        const f16* qptr = Qh + base + (size_t)(q0 + w * 32 + lq) * DK_ + g * 8;
        qf0[0] = *(const f16x8*)(qptr);
        qf0[1] = *(const f16x8*)(qptr + 32);
        qptr += 16 * DK_;
        qf1[0] = *(const f16x8*)(qptr);
        qf1[1] = *(const f16x8*)(qptr + 32);
    }

    const int srow = tid >> 2;              // staging row 0..63
    const int sslot = (tid & 3) * 2;        // logical 16B slot (even)
    const int ps0 = sslot ^ (srow & 7);
    const int ps1 = (sslot + 1) ^ (srow & 7);

    f32x4 acc0[4] = {}, acc1[4] = {};
    float mrun0 = -1e30f, lrun0 = 0.f;
    float mrun1 = -1e30f, lrun1 = 0.f;

    f16x8 kr0, kr1, vr0, vr1;

    auto issue = [&](int k0) {
        const f16* kp = Kh + base + (size_t)(k0 + srow) * DK_ + sslot * 8;
        kr0 = *(const f16x8*)kp;
        kr1 = *(const f16x8*)(kp + 8);
        const f16* vp = VhT + (size_t)(bh * DK_ + srow) * L_ + k0 + sslot * 8;
        vr0 = *(const f16x8*)vp;
        vr1 = *(const f16x8*)(vp + 8);
    };

    auto store_tile = [&](int buf, int k0) {
        *(f16x8*)&Ks[buf][srow * 64 + ps0 * 8] = kr0;
        *(f16x8*)&Ks[buf][srow * 64 + ps1 * 8] = kr1;
        *(f16x8*)&Vt[buf][srow * 64 + ps0 * 8] = vr0;
        *(f16x8*)&Vt[buf][srow * 64 + ps1 * 8] = vr1;
        if (tid < 16) {
            int4 mv = *(const int4*)&maskp[k0 + tid * 4];
            float4 f = { mv.x ? 0.f : MASKOFF, mv.y ? 0.f : MASKOFF,
                         mv.z ? 0.f : MASKOFF, mv.w ? 0.f : MASKOFF };
            *(float4*)&mofft[buf][tid * 4] = f;
        }
    };

    auto softmax_store = [&](float* sv, float& mrun, float& lrun,
                             f32x4* acc, int rowoff) {
        float a0 = fmaxf(sv[0], sv[1]),  a1 = fmaxf(sv[2], sv[3]);
        float a2 = fmaxf(sv[4], sv[5]),  a3 = fmaxf(sv[6], sv[7]);
        float a4 = fmaxf(sv[8], sv[9]),  a5 = fmaxf(sv[10], sv[11]);
        float a6 = fmaxf(sv[12], sv[13]), a7 = fmaxf(sv[14], sv[15]);
        float m = fmaxf(fmaxf(fmaxf(a0, a1), fmaxf(a2, a3)),
                        fmaxf(fmaxf(a4, a5), fmaxf(a6, a7)));
        m = fmaxf(m, __shfl_xor(m, 16, 64));
        m = fmaxf(m, __shfl_xor(m, 32, 64));
        if (__any(m > mrun)) {
            float mn = fmaxf(mrun, m);
            float scl = fast_exp2(mrun - mn);
            mrun = mn;
            lrun *= scl;
            #pragma unroll
            for (int f = 0; f < 4; ++f) acc[f] *= scl;
        }
        f16* pl = (f16*)Plds[w];
        float ls0 = 0.f, ls1 = 0.f;
        #pragma unroll
        for (int kt = 0; kt < 4; ++kt) {
            float p0 = fast_exp2(sv[kt * 4 + 0] - mrun);
            float p1 = fast_exp2(sv[kt * 4 + 1] - mrun);
            float p2 = fast_exp2(sv[kt * 4 + 2] - mrun);
            float p3 = fast_exp2(sv[kt * 4 + 3] - mrun);
            ls0 += p0 + p1;
            ls1 += p2 + p3;
            f16x4 pk = pack4(p0, p1, p2, p3);
            *(f16x4*)&pl[(rowoff + lq) * 72 + kt * 16 + g * 4] = pk;
        }
        lrun += ls0 + ls1;
    };

    auto compute = [&](int buf) {
        float sv0[16], sv1[16];
        __builtin_amdgcn_s_setprio(1);
        #pragma unroll
        for (int kt = 0; kt < 4; ++kt) {
            f32x4 cin = *(const f32x4*)&mofft[buf][kt * 16 + g * 4];
            int row = kt * 16 + lq;
            const f16* kb = &Ks[buf][row * 64];
            f16x8 a0 = *(const f16x8*)&kb[(g ^ (row & 7)) * 8];
            f16x8 a1 = *(const f16x8*)&kb[((g + 4) ^ (row & 7)) * 8];
            f32x4 s0 = __builtin_amdgcn_mfma_f32_16x16x32_f16(a0, qf0[0], cin, 0, 0, 0);
            s0 = __builtin_amdgcn_mfma_f32_16x16x32_f16(a1, qf0[1], s0, 0, 0, 0);
            f32x4 s1 = __builtin_amdgcn_mfma_f32_16x16x32_f16(a0, qf1[0], cin, 0, 0, 0);
            s1 = __builtin_amdgcn_mfma_f32_16x16x32_f16(a1, qf1[1], s1, 0, 0, 0);
            *(f32x4*)&sv0[kt * 4] = s0;
            *(f32x4*)&sv1[kt * 4] = s1;
        }
        __builtin_amdgcn_s_setprio(0);

        softmax_store(sv0, mrun0, lrun0, acc0, 0);
        softmax_store(sv1, mrun1, lrun1, acc1, 16);
        asm volatile("s_waitcnt lgkmcnt(0)" ::: "memory");
        __builtin_amdgcn_sched_barrier(0);

        f16* pl = (f16*)Plds[w];
        __builtin_amdgcn_s_setprio(1);
        #pragma unroll
        for (int kc = 0; kc < 2; ++kc) {
            f16x8 pb0 = *(const f16x8*)&pl[lq * 72 + kc * 32 + g * 8];
            f16x8 pb1 = *(const f16x8*)&pl[(16 + lq) * 72 + kc * 32 + g * 8];
            #pragma unroll
            for (int f = 0; f < 4; ++f) {
                int row = f * 16 + lq;
                f16x8 va = *(const f16x8*)&Vt[buf][row * 64 + ((kc * 4 + g) ^ (row & 7)) * 8];
                acc0[f] = __builtin_amdgcn_mfma_f32_16x16x32_f16(va, pb0, acc0[f], 0, 0, 0);
                acc1[f] = __builtin_amdgcn_mfma_f32_16x16x32_f16(va, pb1, acc1[f], 0, 0, 0);
            }
        }
        __builtin_amdgcn_s_setprio(0);
    };

    issue(0);
    store_tile(0, 0);
    issue(64);
    __syncthreads();

    #pragma unroll 2
    for (int t = 0; t < 32; ++t) {
        int buf = t & 1;
        if (t + 1 < 32) store_tile(buf ^ 1, (t + 1) * 64);
        if (t + 2 < 32) issue((t + 2) * 64);
        compute(buf);
        __syncthreads();
    }

    lrun0 += __shfl_xor(lrun0, 16, 64);
    lrun0 += __shfl_xor(lrun0, 32, 64);
    lrun1 += __shfl_xor(lrun1, 16, 64);
    lrun1 += __shfl_xor(lrun1, 32, 64);
    {
        float inv = 1.f / lrun0;
        int q = q0 + w * 32 + lq;
        #pragma unroll
        for (int f = 0; f < 4; ++f) {
            f16x4 o = { (f16)(acc0[f][0] * inv), (f16)(acc0[f][1] * inv),
                        (f16)(acc0[f][2] * inv), (f16)(acc0[f][3] * inv) };
            *(f16x4*)&Oh[((size_t)(b * L_ + q)) * D_ + h * 64 + f * 16 + g * 4] = o;
        }
    }
    {
        float inv = 1.f / lrun1;
        int q = q0 + w * 32 + 16 + lq;
        #pragma unroll
        for (int f = 0; f < 4; ++f) {
            f16x4 o = { (f16)(acc1[f][0] * inv), (f16)(acc1[f][1] * inv),
                        (f16)(acc1[f][2] * inv), (f16)(acc1[f][3] * inv) };
            *(f16x4*)&Oh[((size_t)(b * L_ + q)) * D_ + h * 64 + f * 16 + g * 4] = o;
        }
    }
}

// ---------------------------------------------------------------------------
// Output projection GEMM (+bias), f32 out. BK=64 as two BK=32 sub-tiles,
// 2 barriers per 64-K step (16 steps), reg prefetch across 32 MFMA.
// ---------------------------------------------------------------------------
__global__ __launch_bounds__(256) void out_proj_kernel(
    const f16* __restrict__ Oh, const float* __restrict__ outw,
    const float* __restrict__ outb, float* __restrict__ Y)
{
    const int m0 = blockIdx.x * 128;
    const int n0 = blockIdx.y * 128;
    const int tid = threadIdx.x;
    const int lane = tid & 63;
    const int w = tid >> 6;
    const int wr = (w >> 1) * 64, wc = (w & 1) * 64;

    __shared__ f16 As[2][128 * 40];
    __shared__ f16 Ws[2][128 * 40];

    f32x4 acc[4][4] = {};

    const int r = tid >> 3, c = (tid & 7) * 4;
    f16x4 ra[2][4];
    float4 rb[2][4];

    auto issueK = [&](int kk) {
        #pragma unroll
        for (int s = 0; s < 2; ++s)
            #pragma unroll
            for (int p = 0; p < 4; ++p) {
                ra[s][p] = *(const f16x4*)&Oh[(size_t)(m0 + p * 32 + r) * D_ + kk + s * 32 + c];
                rb[s][p] = *(const float4*)&outw[(size_t)(n0 + p * 32 + r) * D_ + kk + s * 32 + c];
            }
    };
    auto storeK = [&]() {
        #pragma unroll
        for (int s = 0; s < 2; ++s)
            #pragma unroll
            for (int p = 0; p < 4; ++p) {
                int row = p * 32 + r;
                *(f16x4*)&As[s][row * 40 + c] = ra[s][p];
                f16x4 hb = { (f16)rb[s][p].x, (f16)rb[s][p].y,
                             (f16)rb[s][p].z, (f16)rb[s][p].w };
                *(f16x4*)&Ws[s][row * 40 + c] = hb;
            }
    };

    issueK(0);
    for (int t = 0; t < 16; ++t) {
        __syncthreads();
        storeK();
        if (t + 1 < 16) issueK((t + 1) * 64);
        __syncthreads();

        const int lg = (lane >> 4) * 8;
        #pragma unroll
        for (int s = 0; s < 2; ++s) {
            f16x8 af[4], bf[4];
            #pragma unroll
            for (int i = 0; i < 4; ++i) {
                af[i] = *(const f16x8*)&As[s][(wr + i * 16 + (lane & 15)) * 40 + lg];
                bf[i] = *(const f16x8*)&Ws[s][(wc + i * 16 + (lane & 15)) * 40 + lg];
            }
            #pragma unroll
            for (int i = 0; i < 4; ++i)
                #pragma unroll
                for (int j = 0; j < 4; ++j)
                    acc[i][j] = __builtin_amdgcn_mfma_f32_16x16x32_f16(af[i], bf[j], acc[i][j], 0, 0, 0);
        }
    }

    #pragma unroll
    for (int i = 0; i < 4; ++i) {
        int grow = m0 + wr + i * 16 + (lane >> 4) * 4;
        #pragma unroll
        for (int j = 0; j < 4; ++j) {
            int gcol = n0 + wc + j * 16 + (lane & 15);
            float bias = outb[gcol];
            #pragma unroll
            for (int rr = 0; rr < 4; ++rr)
                Y[(size_t)(grow + rr) * D_ + gcol] = acc[i][j][rr] + bias;
        }
    }
}

extern "C" void kernel_launch(void* const* d_in, const int* in_sizes, int n_in,
                              void* d_out, int out_size, void* d_ws, size_t ws_size,
                              hipStream_t stream) {
    const float* query = (const float*)d_in[0];
    const float* key   = (const float*)d_in[1];
    const float* value = (const float*)d_in[2];
    const float* Wq    = (const float*)d_in[3];
    const float* Wk    = (const float*)d_in[4];
    const float* Wv    = (const float*)d_in[5];
    const float* outw  = (const float*)d_in[7];
    const float* outb  = (const float*)d_in[8];
    const int*   mask  = (const int*)d_in[10];
    float* Y = (float*)d_out;

    char* ws = (char*)d_ws;
    f16* Qh  = (f16*)(ws);                 //  8 MiB: [b,h,l,k] f16 (pre-scaled)
    f16* Kh  = (f16*)(ws + 8388608);       //  8 MiB: [b,h,l,k]
    f16* VhT = (f16*)(ws + 16777216);      //  8 MiB: [b,h,k,l]  (V transposed)
    f16* Oh  = (f16*)(ws + 25165824);      //  8 MiB: [b,l,h*64+k]

    qkv_proj_kernel<<<dim3(32, 8, 3), 256, 0, stream>>>(query, key, value,
                                                        Wq, Wk, Wv, Qh, Kh, VhT);
    attn_kernel<<<dim3(512), 256, 0, stream>>>(Qh, Kh, VhT, mask, Oh);
    out_proj_kernel<<<dim3(32, 8), 256, 0, stream>>>(Oh, outw, outb, Y);
}